// Round 1
// baseline (215.274 us; speedup 1.0000x reference)
//
#include <hip/hip_runtime.h>

// Problem constants (from reference): B=4, T=512, U=100, D=512, C=1024
constexpr int B_ = 4;
constexpr int T_ = 512;
constexpr int U_ = 100;
constexpr int D_ = 512;
constexpr int C_ = 1024;

// ---------------------------------------------------------------------------
// Phase 1: P[m, c] = sum_d A[m, d] * W[c, woff + d]
// A: M x D_ row-major. W: C_ x (2*D_) row-major. P: M x C_ row-major.
// 64x64 output tile per 256-thread block, BK=16, fp32 vector FMA.
// LDS tiles stored transposed [k][m] / [k][c] with +4 pad (keeps 16B align,
// spreads write banks; fragment reads are float4, broadcast across 16-lane
// groups -> conflict-free).
// ---------------------------------------------------------------------------
__global__ __launch_bounds__(256) void proj_gemm(
    const float* __restrict__ A, const float* __restrict__ W,
    float* __restrict__ P, int M, int woff)
{
    constexpr int BM = 64, BN = 64, BK = 16;
    constexpr int LDP = BM + 4;           // 68 floats, 272B (16B-aligned rows)
    __shared__ float As[BK][LDP];
    __shared__ float Bs[BK][LDP];

    const int bm = blockIdx.y * BM;
    const int bn = blockIdx.x * BN;
    const int tid = threadIdx.x;
    const int tx = tid & 15;              // c-fragment group (0..15)
    const int ty = tid >> 4;              // m-fragment group (0..15)

    // staging: each thread loads one float4 of A and one of B per k-tile
    const int srow  = tid >> 2;           // 0..63 (tile row)
    const int scol4 = tid & 3;            // 0..3  (k/4 within tile)

    float acc[4][4] = {};

    for (int k0 = 0; k0 < D_; k0 += BK) {
        // --- A tile (guarded: M may not be a multiple of 64) ---
        float4 av = make_float4(0.f, 0.f, 0.f, 0.f);
        const int m = bm + srow;
        if (m < M)
            av = *reinterpret_cast<const float4*>(&A[(size_t)m * D_ + k0 + scol4 * 4]);
        As[scol4 * 4 + 0][srow] = av.x;
        As[scol4 * 4 + 1][srow] = av.y;
        As[scol4 * 4 + 2][srow] = av.z;
        As[scol4 * 4 + 3][srow] = av.w;

        // --- B tile (W rows always in range: grid.x * BN == C_) ---
        const int c = bn + srow;
        const float4 bv = *reinterpret_cast<const float4*>(
            &W[(size_t)c * (2 * D_) + woff + k0 + scol4 * 4]);
        Bs[scol4 * 4 + 0][srow] = bv.x;
        Bs[scol4 * 4 + 1][srow] = bv.y;
        Bs[scol4 * 4 + 2][srow] = bv.z;
        Bs[scol4 * 4 + 3][srow] = bv.w;

        __syncthreads();

        #pragma unroll
        for (int kk = 0; kk < BK; ++kk) {
            const float4 a4 = *reinterpret_cast<const float4*>(&As[kk][ty * 4]);
            const float4 b4 = *reinterpret_cast<const float4*>(&Bs[kk][tx * 4]);
            const float a[4] = {a4.x, a4.y, a4.z, a4.w};
            const float b[4] = {b4.x, b4.y, b4.z, b4.w};
            #pragma unroll
            for (int i = 0; i < 4; ++i)
                #pragma unroll
                for (int j = 0; j < 4; ++j)
                    acc[i][j] = fmaf(a[i], b[j], acc[i][j]);
        }
        __syncthreads();
    }

    // --- epilogue: float4 stores, guarded on m ---
    #pragma unroll
    for (int i = 0; i < 4; ++i) {
        const int m = bm + ty * 4 + i;
        if (m < M) {
            float4 r = make_float4(acc[i][0], acc[i][1], acc[i][2], acc[i][3]);
            *reinterpret_cast<float4*>(&P[(size_t)m * C_ + bn + tx * 4]) = r;
        }
    }
}

// ---------------------------------------------------------------------------
// Phase 2: out[((b*T + t)*U + u)*C + c] = ep[(b*T+t)*C + c] + dp[(b*U+u)*C + c]
// Block = one (b,t) x 10 u's x full C. 256 threads x float4 = one C row per
// iteration. ep row held in registers; dp rows are L2-resident (1.6 MB total).
// ---------------------------------------------------------------------------
constexpr int UT_ = 10;   // u's per block; U_ % UT_ == 0

__global__ __launch_bounds__(256) void bcast_add(
    const float* __restrict__ ep, const float* __restrict__ dp,
    float* __restrict__ out)
{
    const int bid = blockIdx.x;
    const int ug  = bid % (U_ / UT_);     // u-group 0..9
    const int bt  = bid / (U_ / UT_);     // 0 .. B*T-1
    const int b   = bt / T_;
    const int tid = threadIdx.x;
    const int coff = tid * 4;

    const float4 e = *reinterpret_cast<const float4*>(&ep[(size_t)bt * C_ + coff]);

    const float* dpr = dp + (size_t)(b * U_ + ug * UT_) * C_ + coff;
    float* outp = out + ((size_t)bt * U_ + ug * UT_) * C_ + coff;

    #pragma unroll
    for (int i = 0; i < UT_; ++i) {
        const float4 d = *reinterpret_cast<const float4*>(dpr + (size_t)i * C_);
        const float4 r = make_float4(e.x + d.x, e.y + d.y, e.z + d.z, e.w + d.w);
        *reinterpret_cast<float4*>(outp + (size_t)i * C_) = r;
    }
}

extern "C" void kernel_launch(void* const* d_in, const int* in_sizes, int n_in,
                              void* d_out, int out_size, void* d_ws, size_t ws_size,
                              hipStream_t stream)
{
    const float* enc = (const float*)d_in[0];   // (B, T, D)
    const float* dec = (const float*)d_in[1];   // (B, U, D)
    const float* W   = (const float*)d_in[2];   // (C, 2D)
    float* out = (float*)d_out;                 // (B, T, U, C) fp32

    const int Menc = B_ * T_;   // 2048
    const int Mdec = B_ * U_;   // 400

    const size_t need = (size_t)(Menc + Mdec) * C_ * sizeof(float);  // ~9.6 MB
    if (ws_size < need) return;  // fail loudly (validation) rather than fault

    float* ep = (float*)d_ws;                       // 2048 x 1024
    float* dp = ep + (size_t)Menc * C_;             // 400 x 1024

    // Phase 1: projections
    proj_gemm<<<dim3(C_ / 64, (Menc + 63) / 64), 256, 0, stream>>>(enc, W, ep, Menc, 0);
    proj_gemm<<<dim3(C_ / 64, (Mdec + 63) / 64), 256, 0, stream>>>(dec, W, dp, Mdec, D_);

    // Phase 2: broadcast add (the HBM-bound bulk)
    const int nblk = B_ * T_ * (U_ / UT_);   // 20480
    bcast_add<<<nblk, 256, 0, stream>>>(ep, dp, out);
}

// Round 3
// 182.462 us; speedup vs baseline: 1.1798x; 1.1798x over previous
//
#include <hip/hip_runtime.h>

// Problem constants: B=4, T=512, U=100, D=512, C=1024
constexpr int B_ = 4;
constexpr int T_ = 512;
constexpr int U_ = 100;
constexpr int D_ = 512;
constexpr int C_ = 1024;

typedef short  s16x8 __attribute__((ext_vector_type(8)));
typedef float  f32x4 __attribute__((ext_vector_type(4)));
typedef unsigned short u16x8 __attribute__((ext_vector_type(8)));

// fp32 -> bf16 RNE (finite inputs; no NaN handling needed)
__device__ __forceinline__ unsigned short f2bf(float f) {
    unsigned int u = __float_as_uint(f);
    return (unsigned short)((u + 0x7FFFu + ((u >> 16) & 1u)) >> 16);
}

// ---------------------------------------------------------------------------
// Fused projections via bf16 MFMA.
// P[m,c] = sum_d A[m,d] * W[c, woff+d],  fp32 in -> bf16 (RNE) -> MFMA fp32 acc.
// One launch covers BOTH gemms: grid.y 0..15 -> enc (M=2048, woff=0, dst=ep),
//                               grid.y 16..19 -> dec (M=400,  woff=D, dst=dp).
// 128x128 tile, BK=32, 4 waves (2x2), 64x64 per wave = 4x4 fragments.
// LDS: [row][k] bf16, row pitch 40 elems (80 B) -> 16B-aligned rows.
// ---------------------------------------------------------------------------
__global__ __launch_bounds__(256) void proj_gemm_mfma(
    const float* __restrict__ enc, const float* __restrict__ dec,
    const float* __restrict__ W, float* __restrict__ ep, float* __restrict__ dp)
{
    constexpr int BK  = 32;
    constexpr int LDK = 40;                 // 32 + 8 pad (80 B pitch)
    __shared__ unsigned short As[128 * LDK];
    __shared__ unsigned short Bs[128 * LDK];

    const int by = blockIdx.y;
    const bool is_enc = (by < 16);
    const float* __restrict__ A = is_enc ? enc : dec;
    float* __restrict__ P       = is_enc ? ep : dp;
    const int M    = is_enc ? (B_ * T_) : (B_ * U_);
    const int m0   = (is_enc ? by : (by - 16)) * 128;
    const int woff = is_enc ? 0 : D_;
    const int bn   = blockIdx.x * 128;

    const int tid  = threadIdx.x;
    const int lane = tid & 63;
    const int w    = tid >> 6;              // wave 0..3
    const int wm   = w >> 1;                // 0..1
    const int wn   = w & 1;                 // 0..1
    const int lr   = lane & 15;
    const int lk   = lane >> 4;             // 0..3

    // staging role: 2 threads per row, 16 k-floats each
    const int srow  = tid >> 1;             // 0..127
    const int shalf = tid & 1;              // k 0..15 / 16..31

    f32x4 acc[4][4] = {};

    const float* __restrict__ aBase = A + (size_t)(m0 + srow) * D_ + shalf * 16;
    const float* __restrict__ wBase = W + (size_t)(bn + srow) * (2 * D_) + woff + shalf * 16;
    const bool arow_ok = (m0 + srow) < M;

    for (int kt = 0; kt < D_ / BK; ++kt) {
        if (kt) __syncthreads();
        const int k0 = kt * BK;

        // ---- stage A (guarded) ----
        {
            u16x8 v0 = {}, v1 = {};
            if (arow_ok) {
                const float4 f0 = *reinterpret_cast<const float4*>(aBase + k0 + 0);
                const float4 f1 = *reinterpret_cast<const float4*>(aBase + k0 + 4);
                const float4 f2 = *reinterpret_cast<const float4*>(aBase + k0 + 8);
                const float4 f3 = *reinterpret_cast<const float4*>(aBase + k0 + 12);
                v0 = u16x8{f2bf(f0.x), f2bf(f0.y), f2bf(f0.z), f2bf(f0.w),
                           f2bf(f1.x), f2bf(f1.y), f2bf(f1.z), f2bf(f1.w)};
                v1 = u16x8{f2bf(f2.x), f2bf(f2.y), f2bf(f2.z), f2bf(f2.w),
                           f2bf(f3.x), f2bf(f3.y), f2bf(f3.z), f2bf(f3.w)};
            }
            unsigned short* d = &As[srow * LDK + shalf * 16];
            *reinterpret_cast<u16x8*>(d)     = v0;
            *reinterpret_cast<u16x8*>(d + 8) = v1;
        }
        // ---- stage B (W rows always in range) ----
        {
            const float4 f0 = *reinterpret_cast<const float4*>(wBase + k0 + 0);
            const float4 f1 = *reinterpret_cast<const float4*>(wBase + k0 + 4);
            const float4 f2 = *reinterpret_cast<const float4*>(wBase + k0 + 8);
            const float4 f3 = *reinterpret_cast<const float4*>(wBase + k0 + 12);
            const u16x8 v0 = {f2bf(f0.x), f2bf(f0.y), f2bf(f0.z), f2bf(f0.w),
                              f2bf(f1.x), f2bf(f1.y), f2bf(f1.z), f2bf(f1.w)};
            const u16x8 v1 = {f2bf(f2.x), f2bf(f2.y), f2bf(f2.z), f2bf(f2.w),
                              f2bf(f3.x), f2bf(f3.y), f2bf(f3.z), f2bf(f3.w)};
            unsigned short* d = &Bs[srow * LDK + shalf * 16];
            *reinterpret_cast<u16x8*>(d)     = v0;
            *reinterpret_cast<u16x8*>(d + 8) = v1;
        }
        __syncthreads();

        // ---- fragments + MFMA ----
        s16x8 afrag[4];
        #pragma unroll
        for (int fm = 0; fm < 4; ++fm)
            afrag[fm] = *reinterpret_cast<const s16x8*>(
                &As[(wm * 64 + fm * 16 + lr) * LDK + lk * 8]);
        #pragma unroll
        for (int fn = 0; fn < 4; ++fn) {
            const s16x8 bfrag = *reinterpret_cast<const s16x8*>(
                &Bs[(wn * 64 + fn * 16 + lr) * LDK + lk * 8]);
            #pragma unroll
            for (int fm = 0; fm < 4; ++fm)
                acc[fm][fn] = __builtin_amdgcn_mfma_f32_16x16x32_bf16(
                    afrag[fm], bfrag, acc[fm][fn], 0, 0, 0);
        }
    }

    // ---- epilogue: C/D layout col=lane&15, row=(lane>>4)*4+r ----
    #pragma unroll
    for (int fm = 0; fm < 4; ++fm) {
        #pragma unroll
        for (int r = 0; r < 4; ++r) {
            const int gm = m0 + wm * 64 + fm * 16 + lk * 4 + r;
            if (gm < M) {
                #pragma unroll
                for (int fn = 0; fn < 4; ++fn) {
                    const int c = bn + wn * 64 + fn * 16 + lr;
                    P[(size_t)gm * C_ + c] = acc[fm][fn][r];
                }
            }
        }
    }
}

// ---------------------------------------------------------------------------
// Phase 2: out[((b*T+t)*U+u)*C+c] = ep[(b*T+t)*C+c] + dp[(b*U+u)*C+c]
// Block = one (b,t) x 10 u's x full C; f32x4 loads, nontemporal f32x4
// stores (out is write-once, 839 MB >> L3 -> keep L2 for dp/ep).
// ---------------------------------------------------------------------------
constexpr int UT_ = 10;

__global__ __launch_bounds__(256) void bcast_add(
    const float* __restrict__ ep, const float* __restrict__ dp,
    float* __restrict__ out)
{
    const int bid = blockIdx.x;
    const int ug  = bid % (U_ / UT_);
    const int bt  = bid / (U_ / UT_);
    const int b   = bt / T_;
    const int tid = threadIdx.x;
    const int coff = tid * 4;

    const f32x4 e = *reinterpret_cast<const f32x4*>(&ep[(size_t)bt * C_ + coff]);

    const float* dpr = dp + (size_t)(b * U_ + ug * UT_) * C_ + coff;
    float* outp = out + ((size_t)bt * U_ + ug * UT_) * C_ + coff;

    #pragma unroll
    for (int i = 0; i < UT_; ++i) {
        const f32x4 d = *reinterpret_cast<const f32x4*>(dpr + (size_t)i * C_);
        const f32x4 r = e + d;
        __builtin_nontemporal_store(r, reinterpret_cast<f32x4*>(outp + (size_t)i * C_));
    }
}

extern "C" void kernel_launch(void* const* d_in, const int* in_sizes, int n_in,
                              void* d_out, int out_size, void* d_ws, size_t ws_size,
                              hipStream_t stream)
{
    const float* enc = (const float*)d_in[0];   // (B, T, D)
    const float* dec = (const float*)d_in[1];   // (B, U, D)
    const float* W   = (const float*)d_in[2];   // (C, 2D)
    float* out = (float*)d_out;                 // (B, T, U, C) fp32

    const int Menc = B_ * T_;   // 2048
    const int Mdec = B_ * U_;   // 400

    const size_t need = (size_t)(Menc + Mdec) * C_ * sizeof(float);  // ~9.6 MB
    if (ws_size < need) return;

    float* ep = (float*)d_ws;
    float* dp = ep + (size_t)Menc * C_;

    // Phase 1: both projections in ONE launch (enc: by 0..15, dec: by 16..19)
    proj_gemm_mfma<<<dim3(C_ / 128, 20), 256, 0, stream>>>(enc, dec, W, ep, dp);

    // Phase 2: broadcast add (HBM write-bound bulk)
    const int nblk = B_ * T_ * (U_ / UT_);   // 20480
    bcast_add<<<nblk, 256, 0, stream>>>(ep, dp, out);
}

// Round 4
// 169.466 us; speedup vs baseline: 1.2703x; 1.0767x over previous
//
#include <hip/hip_runtime.h>

// Problem constants: B=4, T=512, U=100, D=512, C=1024
constexpr int B_ = 4;
constexpr int T_ = 512;
constexpr int U_ = 100;
constexpr int D_ = 512;
constexpr int C_ = 1024;

typedef short  s16x8 __attribute__((ext_vector_type(8)));
typedef float  f32x4 __attribute__((ext_vector_type(4)));
typedef unsigned short u16x8 __attribute__((ext_vector_type(8)));

// fp32 -> bf16 RNE (finite inputs; no NaN handling needed)
__device__ __forceinline__ unsigned short f2bf(float f) {
    unsigned int u = __float_as_uint(f);
    return (unsigned short)((u + 0x7FFFu + ((u >> 16) & 1u)) >> 16);
}

// ---------------------------------------------------------------------------
// Fused projections via bf16 MFMA (unchanged from R3: passed, absmax 0.031).
// P[m,c] = sum_d A[m,d] * W[c, woff+d].  grid.y 0..15 -> enc, 16..19 -> dec.
// 128x128 tile, BK=32, 4 waves (2x2), 64x64 per wave = 4x4 fragments.
// ---------------------------------------------------------------------------
__global__ __launch_bounds__(256) void proj_gemm_mfma(
    const float* __restrict__ enc, const float* __restrict__ dec,
    const float* __restrict__ W, float* __restrict__ ep, float* __restrict__ dp)
{
    constexpr int BK  = 32;
    constexpr int LDK = 40;                 // 32 + 8 pad (80 B pitch)
    __shared__ unsigned short As[128 * LDK];
    __shared__ unsigned short Bs[128 * LDK];

    const int by = blockIdx.y;
    const bool is_enc = (by < 16);
    const float* __restrict__ A = is_enc ? enc : dec;
    float* __restrict__ P       = is_enc ? ep : dp;
    const int M    = is_enc ? (B_ * T_) : (B_ * U_);
    const int m0   = (is_enc ? by : (by - 16)) * 128;
    const int woff = is_enc ? 0 : D_;
    const int bn   = blockIdx.x * 128;

    const int tid  = threadIdx.x;
    const int lane = tid & 63;
    const int w    = tid >> 6;
    const int wm   = w >> 1;
    const int wn   = w & 1;
    const int lr   = lane & 15;
    const int lk   = lane >> 4;

    const int srow  = tid >> 1;
    const int shalf = tid & 1;

    f32x4 acc[4][4] = {};

    const float* __restrict__ aBase = A + (size_t)(m0 + srow) * D_ + shalf * 16;
    const float* __restrict__ wBase = W + (size_t)(bn + srow) * (2 * D_) + woff + shalf * 16;
    const bool arow_ok = (m0 + srow) < M;

    for (int kt = 0; kt < D_ / BK; ++kt) {
        if (kt) __syncthreads();
        const int k0 = kt * BK;

        {
            u16x8 v0 = {}, v1 = {};
            if (arow_ok) {
                const float4 f0 = *reinterpret_cast<const float4*>(aBase + k0 + 0);
                const float4 f1 = *reinterpret_cast<const float4*>(aBase + k0 + 4);
                const float4 f2 = *reinterpret_cast<const float4*>(aBase + k0 + 8);
                const float4 f3 = *reinterpret_cast<const float4*>(aBase + k0 + 12);
                v0 = u16x8{f2bf(f0.x), f2bf(f0.y), f2bf(f0.z), f2bf(f0.w),
                           f2bf(f1.x), f2bf(f1.y), f2bf(f1.z), f2bf(f1.w)};
                v1 = u16x8{f2bf(f2.x), f2bf(f2.y), f2bf(f2.z), f2bf(f2.w),
                           f2bf(f3.x), f2bf(f3.y), f2bf(f3.z), f2bf(f3.w)};
            }
            unsigned short* d = &As[srow * LDK + shalf * 16];
            *reinterpret_cast<u16x8*>(d)     = v0;
            *reinterpret_cast<u16x8*>(d + 8) = v1;
        }
        {
            const float4 f0 = *reinterpret_cast<const float4*>(wBase + k0 + 0);
            const float4 f1 = *reinterpret_cast<const float4*>(wBase + k0 + 4);
            const float4 f2 = *reinterpret_cast<const float4*>(wBase + k0 + 8);
            const float4 f3 = *reinterpret_cast<const float4*>(wBase + k0 + 12);
            const u16x8 v0 = {f2bf(f0.x), f2bf(f0.y), f2bf(f0.z), f2bf(f0.w),
                              f2bf(f1.x), f2bf(f1.y), f2bf(f1.z), f2bf(f1.w)};
            const u16x8 v1 = {f2bf(f2.x), f2bf(f2.y), f2bf(f2.z), f2bf(f2.w),
                              f2bf(f3.x), f2bf(f3.y), f2bf(f3.z), f2bf(f3.w)};
            unsigned short* d = &Bs[srow * LDK + shalf * 16];
            *reinterpret_cast<u16x8*>(d)     = v0;
            *reinterpret_cast<u16x8*>(d + 8) = v1;
        }
        __syncthreads();

        s16x8 afrag[4];
        #pragma unroll
        for (int fm = 0; fm < 4; ++fm)
            afrag[fm] = *reinterpret_cast<const s16x8*>(
                &As[(wm * 64 + fm * 16 + lr) * LDK + lk * 8]);
        #pragma unroll
        for (int fn = 0; fn < 4; ++fn) {
            const s16x8 bfrag = *reinterpret_cast<const s16x8*>(
                &Bs[(wn * 64 + fn * 16 + lr) * LDK + lk * 8]);
            #pragma unroll
            for (int fm = 0; fm < 4; ++fm)
                acc[fm][fn] = __builtin_amdgcn_mfma_f32_16x16x32_bf16(
                    afrag[fm], bfrag, acc[fm][fn], 0, 0, 0);
        }
    }

    #pragma unroll
    for (int fm = 0; fm < 4; ++fm) {
        #pragma unroll
        for (int r = 0; r < 4; ++r) {
            const int gm = m0 + wm * 64 + fm * 16 + lk * 4 + r;
            if (gm < M) {
                #pragma unroll
                for (int fn = 0; fn < 4; ++fn) {
                    const int c = bn + wn * 64 + fn * 16 + lr;
                    P[(size_t)gm * C_ + c] = acc[fm][fn][r];
                }
            }
        }
    }
}

// ---------------------------------------------------------------------------
// Phase 2: out[((b*T+t)*U+u)*C+c] = ep[bt*C+c] + dp[(b*U+u)*C+c]
// T1 chunked XCD swizzle: hardware round-robins consecutive blockIdx across
// the 8 XCDs (private, non-coherent L2s). Remap so each XCD owns a
// CONTIGUOUS bt-range -> its ep slice (1 MB) and dp slice (<=800 KB) stay
// L2-resident and are fetched from HBM once, instead of each ep row being
// re-fetched by up to 8 XCDs. NT stores keep the 839 MB write-once stream
// from evicting those slices.
// ---------------------------------------------------------------------------
constexpr int UT_  = 10;
constexpr int NBLK = B_ * T_ * (U_ / UT_);   // 20480, divisible by 8
constexpr int NXCD = 8;

__global__ __launch_bounds__(256) void bcast_add(
    const float* __restrict__ ep, const float* __restrict__ dp,
    float* __restrict__ out)
{
    // chunked XCD swizzle (bijective: NBLK % 8 == 0)
    const int bid  = blockIdx.x;
    const int lbid = (bid & (NXCD - 1)) * (NBLK / NXCD) + (bid >> 3);

    const int ug  = lbid % (U_ / UT_);
    const int bt  = lbid / (U_ / UT_);
    const int b   = bt / T_;
    const int tid = threadIdx.x;
    const int coff = tid * 4;

    const f32x4 e = *reinterpret_cast<const f32x4*>(&ep[(size_t)bt * C_ + coff]);

    const float* dpr = dp + (size_t)(b * U_ + ug * UT_) * C_ + coff;
    float* outp = out + ((size_t)bt * U_ + ug * UT_) * C_ + coff;

    // load all dp rows first (independent -> all in flight), then add+store
    f32x4 d[UT_];
    #pragma unroll
    for (int i = 0; i < UT_; ++i)
        d[i] = *reinterpret_cast<const f32x4*>(dpr + (size_t)i * C_);

    #pragma unroll
    for (int i = 0; i < UT_; ++i) {
        const f32x4 r = e + d[i];
        __builtin_nontemporal_store(r, reinterpret_cast<f32x4*>(outp + (size_t)i * C_));
    }
}

extern "C" void kernel_launch(void* const* d_in, const int* in_sizes, int n_in,
                              void* d_out, int out_size, void* d_ws, size_t ws_size,
                              hipStream_t stream)
{
    const float* enc = (const float*)d_in[0];   // (B, T, D)
    const float* dec = (const float*)d_in[1];   // (B, U, D)
    const float* W   = (const float*)d_in[2];   // (C, 2D)
    float* out = (float*)d_out;                 // (B, T, U, C) fp32

    const int Menc = B_ * T_;   // 2048
    const int Mdec = B_ * U_;   // 400

    const size_t need = (size_t)(Menc + Mdec) * C_ * sizeof(float);  // ~9.6 MB
    if (ws_size < need) return;

    float* ep = (float*)d_ws;
    float* dp = ep + (size_t)Menc * C_;

    // Phase 1: both projections in ONE launch (enc: by 0..15, dec: by 16..19)
    proj_gemm_mfma<<<dim3(C_ / 128, 20), 256, 0, stream>>>(enc, dec, W, ep, dp);

    // Phase 2: broadcast add (HBM write-bound bulk), XCD-swizzled
    bcast_add<<<NBLK, 256, 0, stream>>>(ep, dp, out);
}